// Round 7
// baseline (241.646 us; speedup 1.0000x reference)
//
#include <hip/hip_runtime.h>

// USMSharp R13: vblur with block-shared LDS row panel (reg-staged, NOT
// global_load_lds, NO __launch_bounds__ - R7/R9's failures were launch_bounds
// spill traffic, not LDS itself). Theory: vblur is L3-BW-bound (~8-9 TB/s
// observed at both TV=5 and TV=3); LDS staging cuts the Bh/A re-read 11x->3.5x.
// Each 128-thr block: stage 70 rows x 128 cols bf16 once (19 KB, stride 136
// ushorts = 16B-aligned rows, conv reads 2-way-only conflicts), 1 barrier,
// then R11's identical TV=5 rolling conv from LDS. Reflect applied at stage
// time to same row indices -> bit-identical output.
// hblur kernels: R11 verbatim. vblur geometry: R11 (TBR=20, NYT=54).

#define W 1920
#define H 1080
#define NP 6
#define PLANE (H * W)
#define TOT (NP * PLANE)
#define R 25
#define KS 51
#define TV 5                          // rows per thread
#define TBR 20                        // rows per block = 4 ty-groups * TV
#define TR 70                         // staged rows = TBR + 2*R
#define LSTR 136                      // LDS row stride (ushorts): 272B, 16B-aligned
#define NXT 15
#define NYT 54                        // 1080 / 20
#define WU_TOTAL (NXT * NYT * NP)     // 4860
#define WU_PER_XCD ((WU_TOTAL + 7) / 8)  // 608
#define NROWS (H * NP)                // 6480
#define NI (NROWS * 116)              // interior threads (chunks 2..117)
#define NBI ((NI + 127) / 128)        // 5873  (128-thread blocks)
#define NB (NROWS * 4)                // boundary threads (chunks 0,1,118,119)
#define NBB ((NB + 127) / 128)        // 203

__device__ __forceinline__ int reflect_idx(int i, int n) {
    if (i < 0) i = -i;
    if (i >= n) i = 2 * n - 2 - i;
    return i;
}
__device__ __forceinline__ float bf2f(unsigned short u) {
    return __uint_as_float(((unsigned int)u) << 16);
}
__device__ __forceinline__ unsigned short f2bf(float f) {  // RNE
    unsigned int x = __float_as_uint(f);
    return (unsigned short)((x + 0x7FFFu + ((x >> 16) & 1u)) >> 16);
}
__device__ __forceinline__ float maskf(float f) {
    return (fabsf(f) * 255.f > 10.f) ? 1.f : 0.f;
}

__global__ void compute_k1(const float* __restrict__ k2d, float* __restrict__ k1) {
    int t = threadIdx.x;
    if (t < KS) {
        float s = 0.f;
        for (int j = 0; j < KS; ++j) s += k2d[t * KS + j];
        k1[t] = s;
    }
}

// acc[o] = sum_k k1[k] * w[o+k+7], window w[i] = x[c0-32+i], i in [0,80)
// element p contributes to acc[o], o in [max(0,p-57), min(15,p-7)]
#define CONTRIB(P, VV)                                                   \
    {                                                                    \
        const int _p = (P);                                              \
        if (_p >= 7 && _p <= 72) {                                       \
            const int _olo = (_p - 57 > 0) ? _p - 57 : 0;                \
            const int _ohi = (_p - 7 < 15) ? _p - 7 : 15;                \
            _Pragma("unroll") for (int o = _olo; o <= _ohi; ++o)         \
                acc[o] += k1g[_p - 7 - o] * (VV);                        \
        }                                                                \
    }

template <bool MASK>
__global__ void hblur16(const void* __restrict__ inv, unsigned short* __restrict__ out,
                        const float* __restrict__ k1g) {
    const int b = blockIdx.x;
    float acc[16];
#pragma unroll
    for (int o = 0; o < 16; ++o) acc[o] = 0.f;
    int row, c0;
    if (b < NBI) {  // ---- interior: chunks 2..117, aligned vector loads ----
        const int t = b * 128 + threadIdx.x;
        if (t >= NI) return;
        row = t / 116;
        c0 = (2 + (t - row * 116)) * 16;
        if constexpr (!MASK) {
            const float* rin = (const float*)inv + (size_t)row * W;
#pragma unroll
            for (int i = 0; i < 20; ++i) {
                float4 v = *(const float4*)(rin + c0 - 32 + 4 * i);
                CONTRIB(4 * i + 0, v.x);
                CONTRIB(4 * i + 1, v.y);
                CONTRIB(4 * i + 2, v.z);
                CONTRIB(4 * i + 3, v.w);
            }
        } else {
            const unsigned short* rin = (const unsigned short*)inv + (size_t)row * W;
#pragma unroll
            for (int i = 0; i < 10; ++i) {
                uint4 u = *(const uint4*)(rin + c0 - 32 + 8 * i);
#pragma unroll
                for (int h = 0; h < 4; ++h) {
                    const unsigned int c = (h == 0) ? u.x : (h == 1) ? u.y : (h == 2) ? u.z : u.w;
                    const float flo = __uint_as_float(c << 16);
                    const float fhi = __uint_as_float(c & 0xffff0000u);
                    CONTRIB(8 * i + 2 * h + 0, maskf(flo));
                    CONTRIB(8 * i + 2 * h + 1, maskf(fhi));
                }
            }
        }
    } else {  // ---- boundary: chunks 0,1,118,119, scalar reflect loads ----
        const int t = (b - NBI) * 128 + threadIdx.x;
        if (t >= NB) return;
        row = t >> 2;
        const int q = t & 3;
        c0 = ((q < 2) ? q : q + 116) * 16;
        if constexpr (!MASK) {
            const float* rin = (const float*)inv + (size_t)row * W;
#pragma unroll
            for (int i = 7; i <= 72; ++i) {
                float vv = rin[reflect_idx(c0 - 32 + i, W)];
                CONTRIB(i, vv);
            }
        } else {
            const unsigned short* rin = (const unsigned short*)inv + (size_t)row * W;
#pragma unroll
            for (int i = 7; i <= 72; ++i) {
                float vv = maskf(bf2f(rin[reflect_idx(c0 - 32 + i, W)]));
                CONTRIB(i, vv);
            }
        }
    }
    // pack 16 bf16 -> 2 x 16B stores
    uint4 o0, o1;
    o0.x = (unsigned int)f2bf(acc[0]) | ((unsigned int)f2bf(acc[1]) << 16);
    o0.y = (unsigned int)f2bf(acc[2]) | ((unsigned int)f2bf(acc[3]) << 16);
    o0.z = (unsigned int)f2bf(acc[4]) | ((unsigned int)f2bf(acc[5]) << 16);
    o0.w = (unsigned int)f2bf(acc[6]) | ((unsigned int)f2bf(acc[7]) << 16);
    o1.x = (unsigned int)f2bf(acc[8]) | ((unsigned int)f2bf(acc[9]) << 16);
    o1.y = (unsigned int)f2bf(acc[10]) | ((unsigned int)f2bf(acc[11]) << 16);
    o1.z = (unsigned int)f2bf(acc[12]) | ((unsigned int)f2bf(acc[13]) << 16);
    o1.w = (unsigned int)f2bf(acc[14]) | ((unsigned int)f2bf(acc[15]) << 16);
    unsigned short* op = out + (size_t)row * W + c0;
    *(uint4*)op = o0;
    *(uint4*)(op + 8) = o1;
}

// ---- vertical conv R13: LDS row panel shared by the block ------------------
__device__ __forceinline__ bool decode_wu(int lin, int& p, int& yt, int& xt) {
    int c = lin & 7, j = lin >> 3;
    int wu = c * WU_PER_XCD + j;
    if (wu >= WU_TOTAL) return false;
    p = wu / (NXT * NYT);
    int rem = wu - p * (NXT * NYT);
    yt = rem / NXT;
    xt = rem - yt * NXT;
    return true;
}

// Stage rows [y0b-R, y0b-R+TR) (reflected) of plane Ap, cols [xbase, xbase+128)
// into tile, then per-thread TV=5 rolling conv from LDS. Tap order and input
// values identical to R11's vconvT (reflect applied to same row indices).
__device__ __forceinline__ void vconv_lds(const unsigned short* __restrict__ Ap,
                                          unsigned short* __restrict__ tile,
                                          int xbase, int y0b,
                                          const float* __restrict__ k1g,
                                          float4 acc[TV]) {
    const int lr = threadIdx.x >> 4;         // 0..7: row within 8-row step
    const int lc = (threadIdx.x & 15) * 8;   // ushort col within row (16B lanes)
#pragma unroll
    for (int s = 0; s < 9; ++s) {
        const int r = s * 8 + lr;            // 0..71; 70,71 skipped
        if (r < TR) {
            const int yy = reflect_idx(y0b - R + r, H);
            uint4 v = *(const uint4*)(Ap + (size_t)yy * W + xbase + lc);
            *(uint4*)&tile[r * LSTR + lc] = v;
        }
    }
    __syncthreads();

    const int tx = threadIdx.x & 31, ty = threadIdx.x >> 5;
#pragma unroll
    for (int j = 0; j < TV; ++j) acc[j] = make_float4(0.f, 0.f, 0.f, 0.f);
    const unsigned short* trow = &tile[(ty * TV) * LSTR + tx * 4];
#pragma unroll
    for (int u = 0; u < TV + 2 * R; ++u) {
        ushort4 s = *(const ushort4*)(trow + u * LSTR);  // ds_read_b64 + imm
        float4 v = make_float4(bf2f(s.x), bf2f(s.y), bf2f(s.z), bf2f(s.w));
        const int jlo = (u - 2 * R > 0) ? u - 2 * R : 0;
        const int jhi = (u < TV - 1) ? u : TV - 1;
#pragma unroll
        for (int j = jlo; j <= jhi; ++j) {
            const float k = k1g[u - j];
            acc[j].x += k * v.x; acc[j].y += k * v.y;
            acc[j].z += k * v.z; acc[j].w += k * v.w;
        }
    }
}

__global__ void vblur_r(const unsigned short* __restrict__ A, const float* __restrict__ img,
                        const float* __restrict__ k1g, unsigned short* __restrict__ rbuf) {
    __shared__ unsigned short tile[TR * LSTR];  // 19040 B
    int p, yt, xt;
    if (!decode_wu(blockIdx.x, p, yt, xt)) return;
    const int tx = threadIdx.x & 31, ty = threadIdx.x >> 5;
    const int xbase = xt * 128;
    const int x4 = xbase + tx * 4;
    const int y0 = yt * TBR + ty * TV;
    float4 acc[TV];
    vconv_lds(A + (size_t)p * PLANE, tile, xbase, yt * TBR, k1g, acc);
#pragma unroll
    for (int j = 0; j < TV; ++j) {
        size_t idx = (size_t)p * PLANE + (size_t)(y0 + j) * W + x4;
        float4 iv = *(const float4*)&img[idx];
        ushort4 rr;
        rr.x = f2bf(iv.x - acc[j].x);
        rr.y = f2bf(iv.y - acc[j].y);
        rr.z = f2bf(iv.z - acc[j].z);
        rr.w = f2bf(iv.w - acc[j].w);
        *(ushort4*)&rbuf[idx] = rr;
    }
}

__global__ void vblur_blend(const unsigned short* __restrict__ Bh, const float* __restrict__ img,
                            const unsigned short* __restrict__ rbuf,
                            const float* __restrict__ k1g, float* __restrict__ out) {
    __shared__ unsigned short tile[TR * LSTR];  // 19040 B
    int p, yt, xt;
    if (!decode_wu(blockIdx.x, p, yt, xt)) return;
    const int tx = threadIdx.x & 31, ty = threadIdx.x >> 5;
    const int xbase = xt * 128;
    const int x4 = xbase + tx * 4;
    const int y0 = yt * TBR + ty * TV;
    float4 acc[TV];
    vconv_lds(Bh + (size_t)p * PLANE, tile, xbase, yt * TBR, k1g, acc);
#pragma unroll
    for (int j = 0; j < TV; ++j) {
        size_t idx = (size_t)p * PLANE + (size_t)(y0 + j) * W + x4;
        float4 iv = *(const float4*)&img[idx];
        ushort4 ru = *(const ushort4*)&rbuf[idx];
        float dx = fminf(fmaxf(iv.x + 0.5f * bf2f(ru.x), 0.f), 1.f) - iv.x;
        float dy = fminf(fmaxf(iv.y + 0.5f * bf2f(ru.y), 0.f), 1.f) - iv.y;
        float dz = fminf(fmaxf(iv.z + 0.5f * bf2f(ru.z), 0.f), 1.f) - iv.z;
        float dw = fminf(fmaxf(iv.w + 0.5f * bf2f(ru.w), 0.f), 1.f) - iv.w;
        float4 o;
        o.x = iv.x + acc[j].x * dx;
        o.y = iv.y + acc[j].y * dy;
        o.z = iv.z + acc[j].z * dz;
        o.w = iv.w + acc[j].w * dw;
        *(float4*)&out[idx] = o;
    }
}

extern "C" void kernel_launch(void* const* d_in, const int* in_sizes, int n_in,
                              void* d_out, int out_size, void* d_ws, size_t ws_size,
                              hipStream_t stream) {
    const float* img = (const float*)d_in[0];
    const float* k2d = (const float*)d_in[1];
    float* out = (float*)d_out;

    unsigned short* AB = (unsigned short*)d_ws;  // A, later Bh
    unsigned short* rbuf = AB + TOT;             // residual bf16
    float* k1 = (float*)(rbuf + TOT);

    const int gridHB = NBI + NBB;        // 6076  (128-thread blocks)
    const int gridVB = 8 * WU_PER_XCD;   // 4864  (128-thread blocks)

    hipLaunchKernelGGL(compute_k1, dim3(1), dim3(64), 0, stream, k2d, k1);
    hipLaunchKernelGGL((hblur16<false>), dim3(gridHB), dim3(128), 0, stream, (const void*)img, AB, k1);
    hipLaunchKernelGGL(vblur_r, dim3(gridVB), dim3(128), 0, stream, AB, img, k1, rbuf);
    hipLaunchKernelGGL((hblur16<true>), dim3(gridHB), dim3(128), 0, stream, (const void*)rbuf, AB, k1);
    hipLaunchKernelGGL(vblur_blend, dim3(gridVB), dim3(128), 0, stream, AB, img, rbuf, k1, out);
}

// Round 8
// 228.066 us; speedup vs baseline: 1.0595x; 1.0595x over previous
//
#include <hip/hip_runtime.h>

// USMSharp R14: R11 (best, 200.2us) + issue-early epilogue loads in both
// vblur kernels (T14). LDS staging is permanently dead for vblur: R7/R9/R13
// all showed ~4x WRITE amplification regardless of staging method.
// R13 warm-pass datum: blend duration invariant to read source (all reads
// cached -> same 50us) -> remaining suspect is the serial epilogue tail
// (10 dependent VMEM round-trips per wave after the conv). Hoisting the
// img/rbuf loads BEFORE the conv issues them oldest-first; they retire under
// conv compute; epilogue becomes compute+store only. Pure code motion ->
// bit-identical output.
// K1 hblur16(img f32)->A bf16 ; K2 vblur_r(A) -> r=img-blur bf16
// K3 hblur16(mask(|r|*255>10))->Bh bf16 (aliases A) ; K4 vblur_blend+blend->out.

#define W 1920
#define H 1080
#define NP 6
#define PLANE (H * W)
#define TOT (NP * PLANE)
#define R 25
#define KS 51
#define TV 5                          // rows per thread
#define TBR 20                        // rows per block = 4 ty-groups * TV
#define NXT 15
#define NYT 54                        // 1080 / 20
#define WU_TOTAL (NXT * NYT * NP)     // 4860
#define WU_PER_XCD ((WU_TOTAL + 7) / 8)  // 608
#define NROWS (H * NP)                // 6480
#define NI (NROWS * 116)              // interior threads (chunks 2..117)
#define NBI ((NI + 127) / 128)        // 5873  (128-thread blocks)
#define NB (NROWS * 4)                // boundary threads (chunks 0,1,118,119)
#define NBB ((NB + 127) / 128)        // 203

__device__ __forceinline__ int reflect_idx(int i, int n) {
    if (i < 0) i = -i;
    if (i >= n) i = 2 * n - 2 - i;
    return i;
}
__device__ __forceinline__ float bf2f(unsigned short u) {
    return __uint_as_float(((unsigned int)u) << 16);
}
__device__ __forceinline__ unsigned short f2bf(float f) {  // RNE
    unsigned int x = __float_as_uint(f);
    return (unsigned short)((x + 0x7FFFu + ((x >> 16) & 1u)) >> 16);
}
__device__ __forceinline__ float maskf(float f) {
    return (fabsf(f) * 255.f > 10.f) ? 1.f : 0.f;
}

__global__ void compute_k1(const float* __restrict__ k2d, float* __restrict__ k1) {
    int t = threadIdx.x;
    if (t < KS) {
        float s = 0.f;
        for (int j = 0; j < KS; ++j) s += k2d[t * KS + j];
        k1[t] = s;
    }
}

// acc[o] = sum_k k1[k] * w[o+k+7], window w[i] = x[c0-32+i], i in [0,80)
// element p contributes to acc[o], o in [max(0,p-57), min(15,p-7)]
#define CONTRIB(P, VV)                                                   \
    {                                                                    \
        const int _p = (P);                                              \
        if (_p >= 7 && _p <= 72) {                                       \
            const int _olo = (_p - 57 > 0) ? _p - 57 : 0;                \
            const int _ohi = (_p - 7 < 15) ? _p - 7 : 15;                \
            _Pragma("unroll") for (int o = _olo; o <= _ohi; ++o)         \
                acc[o] += k1g[_p - 7 - o] * (VV);                        \
        }                                                                \
    }

template <bool MASK>
__global__ void hblur16(const void* __restrict__ inv, unsigned short* __restrict__ out,
                        const float* __restrict__ k1g) {
    const int b = blockIdx.x;
    float acc[16];
#pragma unroll
    for (int o = 0; o < 16; ++o) acc[o] = 0.f;
    int row, c0;
    if (b < NBI) {  // ---- interior: chunks 2..117, aligned vector loads ----
        const int t = b * 128 + threadIdx.x;
        if (t >= NI) return;
        row = t / 116;
        c0 = (2 + (t - row * 116)) * 16;
        if constexpr (!MASK) {
            const float* rin = (const float*)inv + (size_t)row * W;
#pragma unroll
            for (int i = 0; i < 20; ++i) {
                float4 v = *(const float4*)(rin + c0 - 32 + 4 * i);
                CONTRIB(4 * i + 0, v.x);
                CONTRIB(4 * i + 1, v.y);
                CONTRIB(4 * i + 2, v.z);
                CONTRIB(4 * i + 3, v.w);
            }
        } else {
            const unsigned short* rin = (const unsigned short*)inv + (size_t)row * W;
#pragma unroll
            for (int i = 0; i < 10; ++i) {
                uint4 u = *(const uint4*)(rin + c0 - 32 + 8 * i);
#pragma unroll
                for (int h = 0; h < 4; ++h) {
                    const unsigned int c = (h == 0) ? u.x : (h == 1) ? u.y : (h == 2) ? u.z : u.w;
                    const float flo = __uint_as_float(c << 16);
                    const float fhi = __uint_as_float(c & 0xffff0000u);
                    CONTRIB(8 * i + 2 * h + 0, maskf(flo));
                    CONTRIB(8 * i + 2 * h + 1, maskf(fhi));
                }
            }
        }
    } else {  // ---- boundary: chunks 0,1,118,119, scalar reflect loads ----
        const int t = (b - NBI) * 128 + threadIdx.x;
        if (t >= NB) return;
        row = t >> 2;
        const int q = t & 3;
        c0 = ((q < 2) ? q : q + 116) * 16;
        if constexpr (!MASK) {
            const float* rin = (const float*)inv + (size_t)row * W;
#pragma unroll
            for (int i = 7; i <= 72; ++i) {
                float vv = rin[reflect_idx(c0 - 32 + i, W)];
                CONTRIB(i, vv);
            }
        } else {
            const unsigned short* rin = (const unsigned short*)inv + (size_t)row * W;
#pragma unroll
            for (int i = 7; i <= 72; ++i) {
                float vv = maskf(bf2f(rin[reflect_idx(c0 - 32 + i, W)]));
                CONTRIB(i, vv);
            }
        }
    }
    // pack 16 bf16 -> 2 x 16B stores
    uint4 o0, o1;
    o0.x = (unsigned int)f2bf(acc[0]) | ((unsigned int)f2bf(acc[1]) << 16);
    o0.y = (unsigned int)f2bf(acc[2]) | ((unsigned int)f2bf(acc[3]) << 16);
    o0.z = (unsigned int)f2bf(acc[4]) | ((unsigned int)f2bf(acc[5]) << 16);
    o0.w = (unsigned int)f2bf(acc[6]) | ((unsigned int)f2bf(acc[7]) << 16);
    o1.x = (unsigned int)f2bf(acc[8]) | ((unsigned int)f2bf(acc[9]) << 16);
    o1.y = (unsigned int)f2bf(acc[10]) | ((unsigned int)f2bf(acc[11]) << 16);
    o1.z = (unsigned int)f2bf(acc[12]) | ((unsigned int)f2bf(acc[13]) << 16);
    o1.w = (unsigned int)f2bf(acc[14]) | ((unsigned int)f2bf(acc[15]) << 16);
    unsigned short* op = out + (size_t)row * W + c0;
    *(uint4*)op = o0;
    *(uint4*)(op + 8) = o1;
}

// ---- vertical conv: register rolling, TV rows x 4 cols per thread ---------
__device__ __forceinline__ bool decode_wu(int lin, int& p, int& yt, int& xt) {
    int c = lin & 7, j = lin >> 3;
    int wu = c * WU_PER_XCD + j;
    if (wu >= WU_TOTAL) return false;
    p = wu / (NXT * NYT);
    int rem = wu - p * (NXT * NYT);
    yt = rem / NXT;
    xt = rem - yt * NXT;
    return true;
}

__device__ __forceinline__ void vconvT(const unsigned short* __restrict__ Ap, int x4, int y0,
                                       const float* __restrict__ k1g, float4 acc[TV]) {
#pragma unroll
    for (int j = 0; j < TV; ++j) acc[j] = make_float4(0.f, 0.f, 0.f, 0.f);
    if (y0 >= R && y0 + TV - 1 + R < H) {
        const unsigned short* p = Ap + (size_t)(y0 - R) * W + x4;
#pragma unroll
        for (int u = 0; u < TV + 2 * R; ++u) {
            ushort4 s = *(const ushort4*)p;
            p += W;
            float4 v = make_float4(bf2f(s.x), bf2f(s.y), bf2f(s.z), bf2f(s.w));
            const int jlo = (u - 2 * R > 0) ? u - 2 * R : 0;
            const int jhi = (u < TV - 1) ? u : TV - 1;
#pragma unroll
            for (int j = jlo; j <= jhi; ++j) {
                const float k = k1g[u - j];
                acc[j].x += k * v.x; acc[j].y += k * v.y;
                acc[j].z += k * v.z; acc[j].w += k * v.w;
            }
        }
    } else {
#pragma unroll
        for (int u = 0; u < TV + 2 * R; ++u) {
            int yy = reflect_idx(y0 - R + u, H);
            ushort4 s = *(const ushort4*)(Ap + (size_t)yy * W + x4);
            float4 v = make_float4(bf2f(s.x), bf2f(s.y), bf2f(s.z), bf2f(s.w));
            const int jlo = (u - 2 * R > 0) ? u - 2 * R : 0;
            const int jhi = (u < TV - 1) ? u : TV - 1;
#pragma unroll
            for (int j = jlo; j <= jhi; ++j) {
                const float k = k1g[u - j];
                acc[j].x += k * v.x; acc[j].y += k * v.y;
                acc[j].z += k * v.z; acc[j].w += k * v.w;
            }
        }
    }
}

__global__ void vblur_r(const unsigned short* __restrict__ A, const float* __restrict__ img,
                        const float* __restrict__ k1g, unsigned short* __restrict__ rbuf) {
    int p, yt, xt;
    if (!decode_wu(blockIdx.x, p, yt, xt)) return;
    const int tx = threadIdx.x & 31, ty = threadIdx.x >> 5;  // 128 thr: ty 0..3
    const int x4 = xt * 128 + tx * 4;
    const int y0 = yt * TBR + ty * TV;
    const size_t idx0 = (size_t)p * PLANE + (size_t)y0 * W + x4;
    // issue-early: epilogue img loads go out BEFORE the conv (T14); they
    // retire (oldest-first) under the conv's compute.
    float4 iv[TV];
#pragma unroll
    for (int j = 0; j < TV; ++j) iv[j] = *(const float4*)&img[idx0 + (size_t)j * W];
    float4 acc[TV];
    vconvT(A + (size_t)p * PLANE, x4, y0, k1g, acc);
#pragma unroll
    for (int j = 0; j < TV; ++j) {
        ushort4 rr;
        rr.x = f2bf(iv[j].x - acc[j].x);
        rr.y = f2bf(iv[j].y - acc[j].y);
        rr.z = f2bf(iv[j].z - acc[j].z);
        rr.w = f2bf(iv[j].w - acc[j].w);
        *(ushort4*)&rbuf[idx0 + (size_t)j * W] = rr;
    }
}

__global__ void vblur_blend(const unsigned short* __restrict__ Bh, const float* __restrict__ img,
                            const unsigned short* __restrict__ rbuf,
                            const float* __restrict__ k1g, float* __restrict__ out) {
    int p, yt, xt;
    if (!decode_wu(blockIdx.x, p, yt, xt)) return;
    const int tx = threadIdx.x & 31, ty = threadIdx.x >> 5;  // 128 thr: ty 0..3
    const int x4 = xt * 128 + tx * 4;
    const int y0 = yt * TBR + ty * TV;
    const size_t idx0 = (size_t)p * PLANE + (size_t)y0 * W + x4;
    // issue-early epilogue loads (img + rbuf), then conv, then compute+store.
    float4 iv[TV];
    ushort4 ru[TV];
#pragma unroll
    for (int j = 0; j < TV; ++j) {
        iv[j] = *(const float4*)&img[idx0 + (size_t)j * W];
        ru[j] = *(const ushort4*)&rbuf[idx0 + (size_t)j * W];
    }
    float4 acc[TV];
    vconvT(Bh + (size_t)p * PLANE, x4, y0, k1g, acc);
#pragma unroll
    for (int j = 0; j < TV; ++j) {
        float dx = fminf(fmaxf(iv[j].x + 0.5f * bf2f(ru[j].x), 0.f), 1.f) - iv[j].x;
        float dy = fminf(fmaxf(iv[j].y + 0.5f * bf2f(ru[j].y), 0.f), 1.f) - iv[j].y;
        float dz = fminf(fmaxf(iv[j].z + 0.5f * bf2f(ru[j].z), 0.f), 1.f) - iv[j].z;
        float dw = fminf(fmaxf(iv[j].w + 0.5f * bf2f(ru[j].w), 0.f), 1.f) - iv[j].w;
        float4 o;
        o.x = iv[j].x + acc[j].x * dx;
        o.y = iv[j].y + acc[j].y * dy;
        o.z = iv[j].z + acc[j].z * dz;
        o.w = iv[j].w + acc[j].w * dw;
        *(float4*)&out[idx0 + (size_t)j * W] = o;
    }
}

extern "C" void kernel_launch(void* const* d_in, const int* in_sizes, int n_in,
                              void* d_out, int out_size, void* d_ws, size_t ws_size,
                              hipStream_t stream) {
    const float* img = (const float*)d_in[0];
    const float* k2d = (const float*)d_in[1];
    float* out = (float*)d_out;

    unsigned short* AB = (unsigned short*)d_ws;  // A, later Bh
    unsigned short* rbuf = AB + TOT;             // residual bf16
    float* k1 = (float*)(rbuf + TOT);

    const int gridHB = NBI + NBB;        // 6076  (128-thread blocks)
    const int gridVB = 8 * WU_PER_XCD;   // 4864  (128-thread blocks)

    hipLaunchKernelGGL(compute_k1, dim3(1), dim3(64), 0, stream, k2d, k1);
    hipLaunchKernelGGL((hblur16<false>), dim3(gridHB), dim3(128), 0, stream, (const void*)img, AB, k1);
    hipLaunchKernelGGL(vblur_r, dim3(gridVB), dim3(128), 0, stream, AB, img, k1, rbuf);
    hipLaunchKernelGGL((hblur16<true>), dim3(gridHB), dim3(128), 0, stream, (const void*)rbuf, AB, k1);
    hipLaunchKernelGGL(vblur_blend, dim3(gridVB), dim3(128), 0, stream, AB, img, rbuf, k1, out);
}

// Round 9
// 204.330 us; speedup vs baseline: 1.1826x; 1.1162x over previous
//
#include <hip/hip_runtime.h>

// USMSharp R15: R11 (best, 200.2us) + __launch_bounds__(128,2) on vblur
// kernels + issue-early epilogue loads.
// R14 finding: the compiler PINS these kernels at 64 VGPR and spills anything
// extra to scratch (blend WRITE 48.6->116.9MB = exactly iv/ru spill bytes).
// R7/R9/R13's "LDS write amplification" was the same spill signature.
// launch_bounds(128,2) = min 2 waves/EU -> VGPR cap 256: lets the allocator
// hold the early-issued epilogue loads AND deepen the conv load pipeline.
// Occupancy cost none (measured residency is ~8-10 waves/CU already).
// Pure code motion + allocation hint -> bit-identical output.
// K1 hblur16(img f32)->A bf16 ; K2 vblur_r(A) -> r=img-blur bf16
// K3 hblur16(mask(|r|*255>10))->Bh bf16 (aliases A) ; K4 vblur_blend+blend->out.

#define W 1920
#define H 1080
#define NP 6
#define PLANE (H * W)
#define TOT (NP * PLANE)
#define R 25
#define KS 51
#define TV 5                          // rows per thread
#define TBR 20                        // rows per block = 4 ty-groups * TV
#define NXT 15
#define NYT 54                        // 1080 / 20
#define WU_TOTAL (NXT * NYT * NP)     // 4860
#define WU_PER_XCD ((WU_TOTAL + 7) / 8)  // 608
#define NROWS (H * NP)                // 6480
#define NI (NROWS * 116)              // interior threads (chunks 2..117)
#define NBI ((NI + 127) / 128)        // 5873  (128-thread blocks)
#define NB (NROWS * 4)                // boundary threads (chunks 0,1,118,119)
#define NBB ((NB + 127) / 128)        // 203

__device__ __forceinline__ int reflect_idx(int i, int n) {
    if (i < 0) i = -i;
    if (i >= n) i = 2 * n - 2 - i;
    return i;
}
__device__ __forceinline__ float bf2f(unsigned short u) {
    return __uint_as_float(((unsigned int)u) << 16);
}
__device__ __forceinline__ unsigned short f2bf(float f) {  // RNE
    unsigned int x = __float_as_uint(f);
    return (unsigned short)((x + 0x7FFFu + ((x >> 16) & 1u)) >> 16);
}
__device__ __forceinline__ float maskf(float f) {
    return (fabsf(f) * 255.f > 10.f) ? 1.f : 0.f;
}

__global__ void compute_k1(const float* __restrict__ k2d, float* __restrict__ k1) {
    int t = threadIdx.x;
    if (t < KS) {
        float s = 0.f;
        for (int j = 0; j < KS; ++j) s += k2d[t * KS + j];
        k1[t] = s;
    }
}

// acc[o] = sum_k k1[k] * w[o+k+7], window w[i] = x[c0-32+i], i in [0,80)
// element p contributes to acc[o], o in [max(0,p-57), min(15,p-7)]
#define CONTRIB(P, VV)                                                   \
    {                                                                    \
        const int _p = (P);                                              \
        if (_p >= 7 && _p <= 72) {                                       \
            const int _olo = (_p - 57 > 0) ? _p - 57 : 0;                \
            const int _ohi = (_p - 7 < 15) ? _p - 7 : 15;                \
            _Pragma("unroll") for (int o = _olo; o <= _ohi; ++o)         \
                acc[o] += k1g[_p - 7 - o] * (VV);                        \
        }                                                                \
    }

template <bool MASK>
__global__ void hblur16(const void* __restrict__ inv, unsigned short* __restrict__ out,
                        const float* __restrict__ k1g) {
    const int b = blockIdx.x;
    float acc[16];
#pragma unroll
    for (int o = 0; o < 16; ++o) acc[o] = 0.f;
    int row, c0;
    if (b < NBI) {  // ---- interior: chunks 2..117, aligned vector loads ----
        const int t = b * 128 + threadIdx.x;
        if (t >= NI) return;
        row = t / 116;
        c0 = (2 + (t - row * 116)) * 16;
        if constexpr (!MASK) {
            const float* rin = (const float*)inv + (size_t)row * W;
#pragma unroll
            for (int i = 0; i < 20; ++i) {
                float4 v = *(const float4*)(rin + c0 - 32 + 4 * i);
                CONTRIB(4 * i + 0, v.x);
                CONTRIB(4 * i + 1, v.y);
                CONTRIB(4 * i + 2, v.z);
                CONTRIB(4 * i + 3, v.w);
            }
        } else {
            const unsigned short* rin = (const unsigned short*)inv + (size_t)row * W;
#pragma unroll
            for (int i = 0; i < 10; ++i) {
                uint4 u = *(const uint4*)(rin + c0 - 32 + 8 * i);
#pragma unroll
                for (int h = 0; h < 4; ++h) {
                    const unsigned int c = (h == 0) ? u.x : (h == 1) ? u.y : (h == 2) ? u.z : u.w;
                    const float flo = __uint_as_float(c << 16);
                    const float fhi = __uint_as_float(c & 0xffff0000u);
                    CONTRIB(8 * i + 2 * h + 0, maskf(flo));
                    CONTRIB(8 * i + 2 * h + 1, maskf(fhi));
                }
            }
        }
    } else {  // ---- boundary: chunks 0,1,118,119, scalar reflect loads ----
        const int t = (b - NBI) * 128 + threadIdx.x;
        if (t >= NB) return;
        row = t >> 2;
        const int q = t & 3;
        c0 = ((q < 2) ? q : q + 116) * 16;
        if constexpr (!MASK) {
            const float* rin = (const float*)inv + (size_t)row * W;
#pragma unroll
            for (int i = 7; i <= 72; ++i) {
                float vv = rin[reflect_idx(c0 - 32 + i, W)];
                CONTRIB(i, vv);
            }
        } else {
            const unsigned short* rin = (const unsigned short*)inv + (size_t)row * W;
#pragma unroll
            for (int i = 7; i <= 72; ++i) {
                float vv = maskf(bf2f(rin[reflect_idx(c0 - 32 + i, W)]));
                CONTRIB(i, vv);
            }
        }
    }
    // pack 16 bf16 -> 2 x 16B stores
    uint4 o0, o1;
    o0.x = (unsigned int)f2bf(acc[0]) | ((unsigned int)f2bf(acc[1]) << 16);
    o0.y = (unsigned int)f2bf(acc[2]) | ((unsigned int)f2bf(acc[3]) << 16);
    o0.z = (unsigned int)f2bf(acc[4]) | ((unsigned int)f2bf(acc[5]) << 16);
    o0.w = (unsigned int)f2bf(acc[6]) | ((unsigned int)f2bf(acc[7]) << 16);
    o1.x = (unsigned int)f2bf(acc[8]) | ((unsigned int)f2bf(acc[9]) << 16);
    o1.y = (unsigned int)f2bf(acc[10]) | ((unsigned int)f2bf(acc[11]) << 16);
    o1.z = (unsigned int)f2bf(acc[12]) | ((unsigned int)f2bf(acc[13]) << 16);
    o1.w = (unsigned int)f2bf(acc[14]) | ((unsigned int)f2bf(acc[15]) << 16);
    unsigned short* op = out + (size_t)row * W + c0;
    *(uint4*)op = o0;
    *(uint4*)(op + 8) = o1;
}

// ---- vertical conv: register rolling, TV rows x 4 cols per thread ---------
__device__ __forceinline__ bool decode_wu(int lin, int& p, int& yt, int& xt) {
    int c = lin & 7, j = lin >> 3;
    int wu = c * WU_PER_XCD + j;
    if (wu >= WU_TOTAL) return false;
    p = wu / (NXT * NYT);
    int rem = wu - p * (NXT * NYT);
    yt = rem / NXT;
    xt = rem - yt * NXT;
    return true;
}

__device__ __forceinline__ void vconvT(const unsigned short* __restrict__ Ap, int x4, int y0,
                                       const float* __restrict__ k1g, float4 acc[TV]) {
#pragma unroll
    for (int j = 0; j < TV; ++j) acc[j] = make_float4(0.f, 0.f, 0.f, 0.f);
    if (y0 >= R && y0 + TV - 1 + R < H) {
        const unsigned short* p = Ap + (size_t)(y0 - R) * W + x4;
#pragma unroll
        for (int u = 0; u < TV + 2 * R; ++u) {
            ushort4 s = *(const ushort4*)p;
            p += W;
            float4 v = make_float4(bf2f(s.x), bf2f(s.y), bf2f(s.z), bf2f(s.w));
            const int jlo = (u - 2 * R > 0) ? u - 2 * R : 0;
            const int jhi = (u < TV - 1) ? u : TV - 1;
#pragma unroll
            for (int j = jlo; j <= jhi; ++j) {
                const float k = k1g[u - j];
                acc[j].x += k * v.x; acc[j].y += k * v.y;
                acc[j].z += k * v.z; acc[j].w += k * v.w;
            }
        }
    } else {
#pragma unroll
        for (int u = 0; u < TV + 2 * R; ++u) {
            int yy = reflect_idx(y0 - R + u, H);
            ushort4 s = *(const ushort4*)(Ap + (size_t)yy * W + x4);
            float4 v = make_float4(bf2f(s.x), bf2f(s.y), bf2f(s.z), bf2f(s.w));
            const int jlo = (u - 2 * R > 0) ? u - 2 * R : 0;
            const int jhi = (u < TV - 1) ? u : TV - 1;
#pragma unroll
            for (int j = jlo; j <= jhi; ++j) {
                const float k = k1g[u - j];
                acc[j].x += k * v.x; acc[j].y += k * v.y;
                acc[j].z += k * v.z; acc[j].w += k * v.w;
            }
        }
    }
}

__global__ void __launch_bounds__(128, 2)
vblur_r(const unsigned short* __restrict__ A, const float* __restrict__ img,
        const float* __restrict__ k1g, unsigned short* __restrict__ rbuf) {
    int p, yt, xt;
    if (!decode_wu(blockIdx.x, p, yt, xt)) return;
    const int tx = threadIdx.x & 31, ty = threadIdx.x >> 5;  // 128 thr: ty 0..3
    const int x4 = xt * 128 + tx * 4;
    const int y0 = yt * TBR + ty * TV;
    const size_t idx0 = (size_t)p * PLANE + (size_t)y0 * W + x4;
    // issue-early epilogue loads (T14): retire oldest-first under conv compute.
    float4 iv[TV];
#pragma unroll
    for (int j = 0; j < TV; ++j) iv[j] = *(const float4*)&img[idx0 + (size_t)j * W];
    float4 acc[TV];
    vconvT(A + (size_t)p * PLANE, x4, y0, k1g, acc);
#pragma unroll
    for (int j = 0; j < TV; ++j) {
        ushort4 rr;
        rr.x = f2bf(iv[j].x - acc[j].x);
        rr.y = f2bf(iv[j].y - acc[j].y);
        rr.z = f2bf(iv[j].z - acc[j].z);
        rr.w = f2bf(iv[j].w - acc[j].w);
        *(ushort4*)&rbuf[idx0 + (size_t)j * W] = rr;
    }
}

__global__ void __launch_bounds__(128, 2)
vblur_blend(const unsigned short* __restrict__ Bh, const float* __restrict__ img,
            const unsigned short* __restrict__ rbuf,
            const float* __restrict__ k1g, float* __restrict__ out) {
    int p, yt, xt;
    if (!decode_wu(blockIdx.x, p, yt, xt)) return;
    const int tx = threadIdx.x & 31, ty = threadIdx.x >> 5;  // 128 thr: ty 0..3
    const int x4 = xt * 128 + tx * 4;
    const int y0 = yt * TBR + ty * TV;
    const size_t idx0 = (size_t)p * PLANE + (size_t)y0 * W + x4;
    // issue-early epilogue loads (img + rbuf), then conv, then compute+store.
    float4 iv[TV];
    ushort4 ru[TV];
#pragma unroll
    for (int j = 0; j < TV; ++j) {
        iv[j] = *(const float4*)&img[idx0 + (size_t)j * W];
        ru[j] = *(const ushort4*)&rbuf[idx0 + (size_t)j * W];
    }
    float4 acc[TV];
    vconvT(Bh + (size_t)p * PLANE, x4, y0, k1g, acc);
#pragma unroll
    for (int j = 0; j < TV; ++j) {
        float dx = fminf(fmaxf(iv[j].x + 0.5f * bf2f(ru[j].x), 0.f), 1.f) - iv[j].x;
        float dy = fminf(fmaxf(iv[j].y + 0.5f * bf2f(ru[j].y), 0.f), 1.f) - iv[j].y;
        float dz = fminf(fmaxf(iv[j].z + 0.5f * bf2f(ru[j].z), 0.f), 1.f) - iv[j].z;
        float dw = fminf(fmaxf(iv[j].w + 0.5f * bf2f(ru[j].w), 0.f), 1.f) - iv[j].w;
        float4 o;
        o.x = iv[j].x + acc[j].x * dx;
        o.y = iv[j].y + acc[j].y * dy;
        o.z = iv[j].z + acc[j].z * dz;
        o.w = iv[j].w + acc[j].w * dw;
        *(float4*)&out[idx0 + (size_t)j * W] = o;
    }
}

extern "C" void kernel_launch(void* const* d_in, const int* in_sizes, int n_in,
                              void* d_out, int out_size, void* d_ws, size_t ws_size,
                              hipStream_t stream) {
    const float* img = (const float*)d_in[0];
    const float* k2d = (const float*)d_in[1];
    float* out = (float*)d_out;

    unsigned short* AB = (unsigned short*)d_ws;  // A, later Bh
    unsigned short* rbuf = AB + TOT;             // residual bf16
    float* k1 = (float*)(rbuf + TOT);

    const int gridHB = NBI + NBB;        // 6076  (128-thread blocks)
    const int gridVB = 8 * WU_PER_XCD;   // 4864  (128-thread blocks)

    hipLaunchKernelGGL(compute_k1, dim3(1), dim3(64), 0, stream, k2d, k1);
    hipLaunchKernelGGL((hblur16<false>), dim3(gridHB), dim3(128), 0, stream, (const void*)img, AB, k1);
    hipLaunchKernelGGL(vblur_r, dim3(gridVB), dim3(128), 0, stream, AB, img, k1, rbuf);
    hipLaunchKernelGGL((hblur16<true>), dim3(gridHB), dim3(128), 0, stream, (const void*)rbuf, AB, k1);
    hipLaunchKernelGGL(vblur_blend, dim3(gridVB), dim3(128), 0, stream, AB, img, rbuf, k1, out);
}

// Round 10
// 201.968 us; speedup vs baseline: 1.1965x; 1.0117x over previous
//
#include <hip/hip_runtime.h>

// USMSharp R16: selective application of the VGPR-cap lever (R15's confirmed
// win on vblur_blend) + revert of collateral damage.
//  - hblur16 (both): +__launch_bounds__(128,2). VGPR pinned at 36, latency-
//    bound (VALU 24%, HBM 16%, occ 52%), 20 independent float4 loads/thread
//    that the allocator can't keep in flight. Same pathology blend had.
//  - vblur_r: reverted to R11 body (no launch_bounds / early loads) - the
//    R15 treatment regressed it ~10us.
//  - vblur_blend: keeps R15 treatment (dropped out of top-5, 50.6 -> <40).
// Attributes + code motion only -> bit-identical output.
// K1 hblur16(img f32)->A bf16 ; K2 vblur_r(A) -> r=img-blur bf16
// K3 hblur16(mask(|r|*255>10))->Bh bf16 (aliases A) ; K4 vblur_blend+blend->out.

#define W 1920
#define H 1080
#define NP 6
#define PLANE (H * W)
#define TOT (NP * PLANE)
#define R 25
#define KS 51
#define TV 5                          // rows per thread
#define TBR 20                        // rows per block = 4 ty-groups * TV
#define NXT 15
#define NYT 54                        // 1080 / 20
#define WU_TOTAL (NXT * NYT * NP)     // 4860
#define WU_PER_XCD ((WU_TOTAL + 7) / 8)  // 608
#define NROWS (H * NP)                // 6480
#define NI (NROWS * 116)              // interior threads (chunks 2..117)
#define NBI ((NI + 127) / 128)        // 5873  (128-thread blocks)
#define NB (NROWS * 4)                // boundary threads (chunks 0,1,118,119)
#define NBB ((NB + 127) / 128)        // 203

__device__ __forceinline__ int reflect_idx(int i, int n) {
    if (i < 0) i = -i;
    if (i >= n) i = 2 * n - 2 - i;
    return i;
}
__device__ __forceinline__ float bf2f(unsigned short u) {
    return __uint_as_float(((unsigned int)u) << 16);
}
__device__ __forceinline__ unsigned short f2bf(float f) {  // RNE
    unsigned int x = __float_as_uint(f);
    return (unsigned short)((x + 0x7FFFu + ((x >> 16) & 1u)) >> 16);
}
__device__ __forceinline__ float maskf(float f) {
    return (fabsf(f) * 255.f > 10.f) ? 1.f : 0.f;
}

__global__ void compute_k1(const float* __restrict__ k2d, float* __restrict__ k1) {
    int t = threadIdx.x;
    if (t < KS) {
        float s = 0.f;
        for (int j = 0; j < KS; ++j) s += k2d[t * KS + j];
        k1[t] = s;
    }
}

// acc[o] = sum_k k1[k] * w[o+k+7], window w[i] = x[c0-32+i], i in [0,80)
// element p contributes to acc[o], o in [max(0,p-57), min(15,p-7)]
#define CONTRIB(P, VV)                                                   \
    {                                                                    \
        const int _p = (P);                                              \
        if (_p >= 7 && _p <= 72) {                                       \
            const int _olo = (_p - 57 > 0) ? _p - 57 : 0;                \
            const int _ohi = (_p - 7 < 15) ? _p - 7 : 15;                \
            _Pragma("unroll") for (int o = _olo; o <= _ohi; ++o)         \
                acc[o] += k1g[_p - 7 - o] * (VV);                        \
        }                                                                \
    }

template <bool MASK>
__global__ void __launch_bounds__(128, 2)
hblur16(const void* __restrict__ inv, unsigned short* __restrict__ out,
        const float* __restrict__ k1g) {
    const int b = blockIdx.x;
    float acc[16];
#pragma unroll
    for (int o = 0; o < 16; ++o) acc[o] = 0.f;
    int row, c0;
    if (b < NBI) {  // ---- interior: chunks 2..117, aligned vector loads ----
        const int t = b * 128 + threadIdx.x;
        if (t >= NI) return;
        row = t / 116;
        c0 = (2 + (t - row * 116)) * 16;
        if constexpr (!MASK) {
            const float* rin = (const float*)inv + (size_t)row * W;
#pragma unroll
            for (int i = 0; i < 20; ++i) {
                float4 v = *(const float4*)(rin + c0 - 32 + 4 * i);
                CONTRIB(4 * i + 0, v.x);
                CONTRIB(4 * i + 1, v.y);
                CONTRIB(4 * i + 2, v.z);
                CONTRIB(4 * i + 3, v.w);
            }
        } else {
            const unsigned short* rin = (const unsigned short*)inv + (size_t)row * W;
#pragma unroll
            for (int i = 0; i < 10; ++i) {
                uint4 u = *(const uint4*)(rin + c0 - 32 + 8 * i);
#pragma unroll
                for (int h = 0; h < 4; ++h) {
                    const unsigned int c = (h == 0) ? u.x : (h == 1) ? u.y : (h == 2) ? u.z : u.w;
                    const float flo = __uint_as_float(c << 16);
                    const float fhi = __uint_as_float(c & 0xffff0000u);
                    CONTRIB(8 * i + 2 * h + 0, maskf(flo));
                    CONTRIB(8 * i + 2 * h + 1, maskf(fhi));
                }
            }
        }
    } else {  // ---- boundary: chunks 0,1,118,119, scalar reflect loads ----
        const int t = (b - NBI) * 128 + threadIdx.x;
        if (t >= NB) return;
        row = t >> 2;
        const int q = t & 3;
        c0 = ((q < 2) ? q : q + 116) * 16;
        if constexpr (!MASK) {
            const float* rin = (const float*)inv + (size_t)row * W;
#pragma unroll
            for (int i = 7; i <= 72; ++i) {
                float vv = rin[reflect_idx(c0 - 32 + i, W)];
                CONTRIB(i, vv);
            }
        } else {
            const unsigned short* rin = (const unsigned short*)inv + (size_t)row * W;
#pragma unroll
            for (int i = 7; i <= 72; ++i) {
                float vv = maskf(bf2f(rin[reflect_idx(c0 - 32 + i, W)]));
                CONTRIB(i, vv);
            }
        }
    }
    // pack 16 bf16 -> 2 x 16B stores
    uint4 o0, o1;
    o0.x = (unsigned int)f2bf(acc[0]) | ((unsigned int)f2bf(acc[1]) << 16);
    o0.y = (unsigned int)f2bf(acc[2]) | ((unsigned int)f2bf(acc[3]) << 16);
    o0.z = (unsigned int)f2bf(acc[4]) | ((unsigned int)f2bf(acc[5]) << 16);
    o0.w = (unsigned int)f2bf(acc[6]) | ((unsigned int)f2bf(acc[7]) << 16);
    o1.x = (unsigned int)f2bf(acc[8]) | ((unsigned int)f2bf(acc[9]) << 16);
    o1.y = (unsigned int)f2bf(acc[10]) | ((unsigned int)f2bf(acc[11]) << 16);
    o1.z = (unsigned int)f2bf(acc[12]) | ((unsigned int)f2bf(acc[13]) << 16);
    o1.w = (unsigned int)f2bf(acc[14]) | ((unsigned int)f2bf(acc[15]) << 16);
    unsigned short* op = out + (size_t)row * W + c0;
    *(uint4*)op = o0;
    *(uint4*)(op + 8) = o1;
}

// ---- vertical conv: register rolling, TV rows x 4 cols per thread ---------
__device__ __forceinline__ bool decode_wu(int lin, int& p, int& yt, int& xt) {
    int c = lin & 7, j = lin >> 3;
    int wu = c * WU_PER_XCD + j;
    if (wu >= WU_TOTAL) return false;
    p = wu / (NXT * NYT);
    int rem = wu - p * (NXT * NYT);
    yt = rem / NXT;
    xt = rem - yt * NXT;
    return true;
}

__device__ __forceinline__ void vconvT(const unsigned short* __restrict__ Ap, int x4, int y0,
                                       const float* __restrict__ k1g, float4 acc[TV]) {
#pragma unroll
    for (int j = 0; j < TV; ++j) acc[j] = make_float4(0.f, 0.f, 0.f, 0.f);
    if (y0 >= R && y0 + TV - 1 + R < H) {
        const unsigned short* p = Ap + (size_t)(y0 - R) * W + x4;
#pragma unroll
        for (int u = 0; u < TV + 2 * R; ++u) {
            ushort4 s = *(const ushort4*)p;
            p += W;
            float4 v = make_float4(bf2f(s.x), bf2f(s.y), bf2f(s.z), bf2f(s.w));
            const int jlo = (u - 2 * R > 0) ? u - 2 * R : 0;
            const int jhi = (u < TV - 1) ? u : TV - 1;
#pragma unroll
            for (int j = jlo; j <= jhi; ++j) {
                const float k = k1g[u - j];
                acc[j].x += k * v.x; acc[j].y += k * v.y;
                acc[j].z += k * v.z; acc[j].w += k * v.w;
            }
        }
    } else {
#pragma unroll
        for (int u = 0; u < TV + 2 * R; ++u) {
            int yy = reflect_idx(y0 - R + u, H);
            ushort4 s = *(const ushort4*)(Ap + (size_t)yy * W + x4);
            float4 v = make_float4(bf2f(s.x), bf2f(s.y), bf2f(s.z), bf2f(s.w));
            const int jlo = (u - 2 * R > 0) ? u - 2 * R : 0;
            const int jhi = (u < TV - 1) ? u : TV - 1;
#pragma unroll
            for (int j = jlo; j <= jhi; ++j) {
                const float k = k1g[u - j];
                acc[j].x += k * v.x; acc[j].y += k * v.y;
                acc[j].z += k * v.z; acc[j].w += k * v.w;
            }
        }
    }
}

__global__ void vblur_r(const unsigned short* __restrict__ A, const float* __restrict__ img,
                        const float* __restrict__ k1g, unsigned short* __restrict__ rbuf) {
    int p, yt, xt;
    if (!decode_wu(blockIdx.x, p, yt, xt)) return;
    const int tx = threadIdx.x & 31, ty = threadIdx.x >> 5;  // 128 thr: ty 0..3
    const int x4 = xt * 128 + tx * 4;
    const int y0 = yt * TBR + ty * TV;
    float4 acc[TV];
    vconvT(A + (size_t)p * PLANE, x4, y0, k1g, acc);
#pragma unroll
    for (int j = 0; j < TV; ++j) {
        size_t idx = (size_t)p * PLANE + (size_t)(y0 + j) * W + x4;
        float4 iv = *(const float4*)&img[idx];
        ushort4 rr;
        rr.x = f2bf(iv.x - acc[j].x);
        rr.y = f2bf(iv.y - acc[j].y);
        rr.z = f2bf(iv.z - acc[j].z);
        rr.w = f2bf(iv.w - acc[j].w);
        *(ushort4*)&rbuf[idx] = rr;
    }
}

__global__ void __launch_bounds__(128, 2)
vblur_blend(const unsigned short* __restrict__ Bh, const float* __restrict__ img,
            const unsigned short* __restrict__ rbuf,
            const float* __restrict__ k1g, float* __restrict__ out) {
    int p, yt, xt;
    if (!decode_wu(blockIdx.x, p, yt, xt)) return;
    const int tx = threadIdx.x & 31, ty = threadIdx.x >> 5;  // 128 thr: ty 0..3
    const int x4 = xt * 128 + tx * 4;
    const int y0 = yt * TBR + ty * TV;
    const size_t idx0 = (size_t)p * PLANE + (size_t)y0 * W + x4;
    // issue-early epilogue loads (img + rbuf), then conv, then compute+store.
    float4 iv[TV];
    ushort4 ru[TV];
#pragma unroll
    for (int j = 0; j < TV; ++j) {
        iv[j] = *(const float4*)&img[idx0 + (size_t)j * W];
        ru[j] = *(const ushort4*)&rbuf[idx0 + (size_t)j * W];
    }
    float4 acc[TV];
    vconvT(Bh + (size_t)p * PLANE, x4, y0, k1g, acc);
#pragma unroll
    for (int j = 0; j < TV; ++j) {
        float dx = fminf(fmaxf(iv[j].x + 0.5f * bf2f(ru[j].x), 0.f), 1.f) - iv[j].x;
        float dy = fminf(fmaxf(iv[j].y + 0.5f * bf2f(ru[j].y), 0.f), 1.f) - iv[j].y;
        float dz = fminf(fmaxf(iv[j].z + 0.5f * bf2f(ru[j].z), 0.f), 1.f) - iv[j].z;
        float dw = fminf(fmaxf(iv[j].w + 0.5f * bf2f(ru[j].w), 0.f), 1.f) - iv[j].w;
        float4 o;
        o.x = iv[j].x + acc[j].x * dx;
        o.y = iv[j].y + acc[j].y * dy;
        o.z = iv[j].z + acc[j].z * dz;
        o.w = iv[j].w + acc[j].w * dw;
        *(float4*)&out[idx0 + (size_t)j * W] = o;
    }
}

extern "C" void kernel_launch(void* const* d_in, const int* in_sizes, int n_in,
                              void* d_out, int out_size, void* d_ws, size_t ws_size,
                              hipStream_t stream) {
    const float* img = (const float*)d_in[0];
    const float* k2d = (const float*)d_in[1];
    float* out = (float*)d_out;

    unsigned short* AB = (unsigned short*)d_ws;  // A, later Bh
    unsigned short* rbuf = AB + TOT;             // residual bf16
    float* k1 = (float*)(rbuf + TOT);

    const int gridHB = NBI + NBB;        // 6076  (128-thread blocks)
    const int gridVB = 8 * WU_PER_XCD;   // 4864  (128-thread blocks)

    hipLaunchKernelGGL(compute_k1, dim3(1), dim3(64), 0, stream, k2d, k1);
    hipLaunchKernelGGL((hblur16<false>), dim3(gridHB), dim3(128), 0, stream, (const void*)img, AB, k1);
    hipLaunchKernelGGL(vblur_r, dim3(gridVB), dim3(128), 0, stream, AB, img, k1, rbuf);
    hipLaunchKernelGGL((hblur16<true>), dim3(gridHB), dim3(128), 0, stream, (const void*)rbuf, AB, k1);
    hipLaunchKernelGGL(vblur_blend, dim3(gridVB), dim3(128), 0, stream, AB, img, rbuf, k1, out);
}

// Round 11
// 201.725 us; speedup vs baseline: 1.1979x; 1.0012x over previous
//
#include <hip/hip_runtime.h>

// USMSharp R17: full two-piece MLP recipe on hblur16.
// R16 lesson: launch_bounds alone doesn't raise VGPR use (32 regs, 42us,
// unchanged) - the compiler needs SOURCE-forced live ranges. R15's blend win
// had both pieces: explicit load arrays + launch_bounds. R17 gives hblur16
// both: interior path batch-loads all 20 float4 (/10 uint4) into arrays,
// then runs the CONTRIB chain in identical i-order (bit-identical).
// vblur_r: R11 body (known good). vblur_blend: R15 body (proven win).
// K1 hblur16(img f32)->A bf16 ; K2 vblur_r(A) -> r=img-blur bf16
// K3 hblur16(mask(|r|*255>10))->Bh bf16 (aliases A) ; K4 vblur_blend+blend->out.

#define W 1920
#define H 1080
#define NP 6
#define PLANE (H * W)
#define TOT (NP * PLANE)
#define R 25
#define KS 51
#define TV 5                          // rows per thread
#define TBR 20                        // rows per block = 4 ty-groups * TV
#define NXT 15
#define NYT 54                        // 1080 / 20
#define WU_TOTAL (NXT * NYT * NP)     // 4860
#define WU_PER_XCD ((WU_TOTAL + 7) / 8)  // 608
#define NROWS (H * NP)                // 6480
#define NI (NROWS * 116)              // interior threads (chunks 2..117)
#define NBI ((NI + 127) / 128)        // 5873  (128-thread blocks)
#define NB (NROWS * 4)                // boundary threads (chunks 0,1,118,119)
#define NBB ((NB + 127) / 128)        // 203

__device__ __forceinline__ int reflect_idx(int i, int n) {
    if (i < 0) i = -i;
    if (i >= n) i = 2 * n - 2 - i;
    return i;
}
__device__ __forceinline__ float bf2f(unsigned short u) {
    return __uint_as_float(((unsigned int)u) << 16);
}
__device__ __forceinline__ unsigned short f2bf(float f) {  // RNE
    unsigned int x = __float_as_uint(f);
    return (unsigned short)((x + 0x7FFFu + ((x >> 16) & 1u)) >> 16);
}
__device__ __forceinline__ float maskf(float f) {
    return (fabsf(f) * 255.f > 10.f) ? 1.f : 0.f;
}

__global__ void compute_k1(const float* __restrict__ k2d, float* __restrict__ k1) {
    int t = threadIdx.x;
    if (t < KS) {
        float s = 0.f;
        for (int j = 0; j < KS; ++j) s += k2d[t * KS + j];
        k1[t] = s;
    }
}

// acc[o] = sum_k k1[k] * w[o+k+7], window w[i] = x[c0-32+i], i in [0,80)
// element p contributes to acc[o], o in [max(0,p-57), min(15,p-7)]
#define CONTRIB(P, VV)                                                   \
    {                                                                    \
        const int _p = (P);                                              \
        if (_p >= 7 && _p <= 72) {                                       \
            const int _olo = (_p - 57 > 0) ? _p - 57 : 0;                \
            const int _ohi = (_p - 7 < 15) ? _p - 7 : 15;                \
            _Pragma("unroll") for (int o = _olo; o <= _ohi; ++o)         \
                acc[o] += k1g[_p - 7 - o] * (VV);                        \
        }                                                                \
    }

template <bool MASK>
__global__ void __launch_bounds__(128, 2)
hblur16(const void* __restrict__ inv, unsigned short* __restrict__ out,
        const float* __restrict__ k1g) {
    const int b = blockIdx.x;
    float acc[16];
#pragma unroll
    for (int o = 0; o < 16; ++o) acc[o] = 0.f;
    int row, c0;
    if (b < NBI) {  // ---- interior: chunks 2..117, batched vector loads ----
        const int t = b * 128 + threadIdx.x;
        if (t >= NI) return;
        row = t / 116;
        c0 = (2 + (t - row * 116)) * 16;
        if constexpr (!MASK) {
            const float* rin = (const float*)inv + (size_t)row * W;
            // batch ALL 20 loads into explicit live ranges (R15 recipe piece 1;
            // launch_bounds above is piece 2 - prevents the spill R14 hit).
            float4 v[20];
#pragma unroll
            for (int i = 0; i < 20; ++i) v[i] = *(const float4*)(rin + c0 - 32 + 4 * i);
#pragma unroll
            for (int i = 0; i < 20; ++i) {
                CONTRIB(4 * i + 0, v[i].x);
                CONTRIB(4 * i + 1, v[i].y);
                CONTRIB(4 * i + 2, v[i].z);
                CONTRIB(4 * i + 3, v[i].w);
            }
        } else {
            const unsigned short* rin = (const unsigned short*)inv + (size_t)row * W;
            uint4 u[10];
#pragma unroll
            for (int i = 0; i < 10; ++i) u[i] = *(const uint4*)(rin + c0 - 32 + 8 * i);
#pragma unroll
            for (int i = 0; i < 10; ++i) {
#pragma unroll
                for (int h = 0; h < 4; ++h) {
                    const unsigned int c = (h == 0) ? u[i].x : (h == 1) ? u[i].y : (h == 2) ? u[i].z : u[i].w;
                    const float flo = __uint_as_float(c << 16);
                    const float fhi = __uint_as_float(c & 0xffff0000u);
                    CONTRIB(8 * i + 2 * h + 0, maskf(flo));
                    CONTRIB(8 * i + 2 * h + 1, maskf(fhi));
                }
            }
        }
    } else {  // ---- boundary: chunks 0,1,118,119, scalar reflect loads ----
        const int t = (b - NBI) * 128 + threadIdx.x;
        if (t >= NB) return;
        row = t >> 2;
        const int q = t & 3;
        c0 = ((q < 2) ? q : q + 116) * 16;
        if constexpr (!MASK) {
            const float* rin = (const float*)inv + (size_t)row * W;
#pragma unroll
            for (int i = 7; i <= 72; ++i) {
                float vv = rin[reflect_idx(c0 - 32 + i, W)];
                CONTRIB(i, vv);
            }
        } else {
            const unsigned short* rin = (const unsigned short*)inv + (size_t)row * W;
#pragma unroll
            for (int i = 7; i <= 72; ++i) {
                float vv = maskf(bf2f(rin[reflect_idx(c0 - 32 + i, W)]));
                CONTRIB(i, vv);
            }
        }
    }
    // pack 16 bf16 -> 2 x 16B stores
    uint4 o0, o1;
    o0.x = (unsigned int)f2bf(acc[0]) | ((unsigned int)f2bf(acc[1]) << 16);
    o0.y = (unsigned int)f2bf(acc[2]) | ((unsigned int)f2bf(acc[3]) << 16);
    o0.z = (unsigned int)f2bf(acc[4]) | ((unsigned int)f2bf(acc[5]) << 16);
    o0.w = (unsigned int)f2bf(acc[6]) | ((unsigned int)f2bf(acc[7]) << 16);
    o1.x = (unsigned int)f2bf(acc[8]) | ((unsigned int)f2bf(acc[9]) << 16);
    o1.y = (unsigned int)f2bf(acc[10]) | ((unsigned int)f2bf(acc[11]) << 16);
    o1.z = (unsigned int)f2bf(acc[12]) | ((unsigned int)f2bf(acc[13]) << 16);
    o1.w = (unsigned int)f2bf(acc[14]) | ((unsigned int)f2bf(acc[15]) << 16);
    unsigned short* op = out + (size_t)row * W + c0;
    *(uint4*)op = o0;
    *(uint4*)(op + 8) = o1;
}

// ---- vertical conv: register rolling, TV rows x 4 cols per thread ---------
__device__ __forceinline__ bool decode_wu(int lin, int& p, int& yt, int& xt) {
    int c = lin & 7, j = lin >> 3;
    int wu = c * WU_PER_XCD + j;
    if (wu >= WU_TOTAL) return false;
    p = wu / (NXT * NYT);
    int rem = wu - p * (NXT * NYT);
    yt = rem / NXT;
    xt = rem - yt * NXT;
    return true;
}

__device__ __forceinline__ void vconvT(const unsigned short* __restrict__ Ap, int x4, int y0,
                                       const float* __restrict__ k1g, float4 acc[TV]) {
#pragma unroll
    for (int j = 0; j < TV; ++j) acc[j] = make_float4(0.f, 0.f, 0.f, 0.f);
    if (y0 >= R && y0 + TV - 1 + R < H) {
        const unsigned short* p = Ap + (size_t)(y0 - R) * W + x4;
#pragma unroll
        for (int u = 0; u < TV + 2 * R; ++u) {
            ushort4 s = *(const ushort4*)p;
            p += W;
            float4 v = make_float4(bf2f(s.x), bf2f(s.y), bf2f(s.z), bf2f(s.w));
            const int jlo = (u - 2 * R > 0) ? u - 2 * R : 0;
            const int jhi = (u < TV - 1) ? u : TV - 1;
#pragma unroll
            for (int j = jlo; j <= jhi; ++j) {
                const float k = k1g[u - j];
                acc[j].x += k * v.x; acc[j].y += k * v.y;
                acc[j].z += k * v.z; acc[j].w += k * v.w;
            }
        }
    } else {
#pragma unroll
        for (int u = 0; u < TV + 2 * R; ++u) {
            int yy = reflect_idx(y0 - R + u, H);
            ushort4 s = *(const ushort4*)(Ap + (size_t)yy * W + x4);
            float4 v = make_float4(bf2f(s.x), bf2f(s.y), bf2f(s.z), bf2f(s.w));
            const int jlo = (u - 2 * R > 0) ? u - 2 * R : 0;
            const int jhi = (u < TV - 1) ? u : TV - 1;
#pragma unroll
            for (int j = jlo; j <= jhi; ++j) {
                const float k = k1g[u - j];
                acc[j].x += k * v.x; acc[j].y += k * v.y;
                acc[j].z += k * v.z; acc[j].w += k * v.w;
            }
        }
    }
}

__global__ void vblur_r(const unsigned short* __restrict__ A, const float* __restrict__ img,
                        const float* __restrict__ k1g, unsigned short* __restrict__ rbuf) {
    int p, yt, xt;
    if (!decode_wu(blockIdx.x, p, yt, xt)) return;
    const int tx = threadIdx.x & 31, ty = threadIdx.x >> 5;  // 128 thr: ty 0..3
    const int x4 = xt * 128 + tx * 4;
    const int y0 = yt * TBR + ty * TV;
    float4 acc[TV];
    vconvT(A + (size_t)p * PLANE, x4, y0, k1g, acc);
#pragma unroll
    for (int j = 0; j < TV; ++j) {
        size_t idx = (size_t)p * PLANE + (size_t)(y0 + j) * W + x4;
        float4 iv = *(const float4*)&img[idx];
        ushort4 rr;
        rr.x = f2bf(iv.x - acc[j].x);
        rr.y = f2bf(iv.y - acc[j].y);
        rr.z = f2bf(iv.z - acc[j].z);
        rr.w = f2bf(iv.w - acc[j].w);
        *(ushort4*)&rbuf[idx] = rr;
    }
}

__global__ void __launch_bounds__(128, 2)
vblur_blend(const unsigned short* __restrict__ Bh, const float* __restrict__ img,
            const unsigned short* __restrict__ rbuf,
            const float* __restrict__ k1g, float* __restrict__ out) {
    int p, yt, xt;
    if (!decode_wu(blockIdx.x, p, yt, xt)) return;
    const int tx = threadIdx.x & 31, ty = threadIdx.x >> 5;  // 128 thr: ty 0..3
    const int x4 = xt * 128 + tx * 4;
    const int y0 = yt * TBR + ty * TV;
    const size_t idx0 = (size_t)p * PLANE + (size_t)y0 * W + x4;
    // issue-early epilogue loads (img + rbuf), then conv, then compute+store.
    float4 iv[TV];
    ushort4 ru[TV];
#pragma unroll
    for (int j = 0; j < TV; ++j) {
        iv[j] = *(const float4*)&img[idx0 + (size_t)j * W];
        ru[j] = *(const ushort4*)&rbuf[idx0 + (size_t)j * W];
    }
    float4 acc[TV];
    vconvT(Bh + (size_t)p * PLANE, x4, y0, k1g, acc);
#pragma unroll
    for (int j = 0; j < TV; ++j) {
        float dx = fminf(fmaxf(iv[j].x + 0.5f * bf2f(ru[j].x), 0.f), 1.f) - iv[j].x;
        float dy = fminf(fmaxf(iv[j].y + 0.5f * bf2f(ru[j].y), 0.f), 1.f) - iv[j].y;
        float dz = fminf(fmaxf(iv[j].z + 0.5f * bf2f(ru[j].z), 0.f), 1.f) - iv[j].z;
        float dw = fminf(fmaxf(iv[j].w + 0.5f * bf2f(ru[j].w), 0.f), 1.f) - iv[j].w;
        float4 o;
        o.x = iv[j].x + acc[j].x * dx;
        o.y = iv[j].y + acc[j].y * dy;
        o.z = iv[j].z + acc[j].z * dz;
        o.w = iv[j].w + acc[j].w * dw;
        *(float4*)&out[idx0 + (size_t)j * W] = o;
    }
}

extern "C" void kernel_launch(void* const* d_in, const int* in_sizes, int n_in,
                              void* d_out, int out_size, void* d_ws, size_t ws_size,
                              hipStream_t stream) {
    const float* img = (const float*)d_in[0];
    const float* k2d = (const float*)d_in[1];
    float* out = (float*)d_out;

    unsigned short* AB = (unsigned short*)d_ws;  // A, later Bh
    unsigned short* rbuf = AB + TOT;             // residual bf16
    float* k1 = (float*)(rbuf + TOT);

    const int gridHB = NBI + NBB;        // 6076  (128-thread blocks)
    const int gridVB = 8 * WU_PER_XCD;   // 4864  (128-thread blocks)

    hipLaunchKernelGGL(compute_k1, dim3(1), dim3(64), 0, stream, k2d, k1);
    hipLaunchKernelGGL((hblur16<false>), dim3(gridHB), dim3(128), 0, stream, (const void*)img, AB, k1);
    hipLaunchKernelGGL(vblur_r, dim3(gridVB), dim3(128), 0, stream, AB, img, k1, rbuf);
    hipLaunchKernelGGL((hblur16<true>), dim3(gridHB), dim3(128), 0, stream, (const void*)rbuf, AB, k1);
    hipLaunchKernelGGL(vblur_blend, dim3(gridVB), dim3(128), 0, stream, AB, img, rbuf, k1, out);
}